// Round 5
// baseline (14.977 us; speedup 1.0000x reference)
//
#include <hip/hip_runtime.h>
#include <math.h>

#define C_CH    192
#define HW_     1024
#define NPLANE  1536           // 8*192 planes of H*W=1024
#define TOTAL_  1572864        // 8*192*32*32
#define PPB     2              // fallback kernel: planes per block
#define NBLK    (NPLANE / PPB)

#define LOG2E   1.4426950408889634f
#define KSOS    28.853900817779268f   /* 2*BETA*log2(e) = 20*log2(e) */
#define INV_D   2.95f                 /* 59/20: inverse spacing of sos_b grid */

#define LUT_L   512
#define LUT_X0  (-10.72f)
#define LUT_SPAN 21.44f
#define LUT_H   (LUT_SPAN / (LUT_L - 1))
#define LUT_IH  ((LUT_L - 1) / LUT_SPAN)

__device__ __forceinline__ float rcp_f(float v)  { return __builtin_amdgcn_rcpf(v); }
__device__ __forceinline__ float exp2_f(float v) { return __builtin_amdgcn_exp2f(v); }

__device__ __forceinline__ float fast_tanh(float z) {
  float e = exp2_f(z * (2.0f * LOG2E));
  return 1.0f - 2.0f * rcp_f(e + 1.0f);
}
__device__ __forceinline__ float fast_sigmoid(float z) {
  return rcp_f(1.0f + exp2_f(-z * LOG2E));
}
__device__ __forceinline__ float softplus_f(float v) {
  return log1pf(expf(v));
}

// s_p layout: [0..8]=sp1 [9..17]=sp2 [18..26]=sp3 [27..29]=sp0 [30..32]=sp4
//             [33..35]=b0 [36..38]=b1 [39..41]=b2 [42..44]=b3 [45]=b4
//             [46..48]=tf0 [49..51]=tf1 [52..54]=tf2 [55..57]=tf3
__device__ __forceinline__ float mlp_full(float v, const float* P) {
  float t, a0, a1, a2, d0, d1, d2;
  t = fmaf(P[27], v, P[33]); a0 = fmaf(P[46], fast_tanh(t), t);
  t = fmaf(P[28], v, P[34]); a1 = fmaf(P[47], fast_tanh(t), t);
  t = fmaf(P[29], v, P[35]); a2 = fmaf(P[48], fast_tanh(t), t);

  t = fmaf(P[2], a2, fmaf(P[1], a1, fmaf(P[0], a0, P[36]))); d0 = fmaf(P[49], fast_tanh(t), t);
  t = fmaf(P[5], a2, fmaf(P[4], a1, fmaf(P[3], a0, P[37]))); d1 = fmaf(P[50], fast_tanh(t), t);
  t = fmaf(P[8], a2, fmaf(P[7], a1, fmaf(P[6], a0, P[38]))); d2 = fmaf(P[51], fast_tanh(t), t);

  t = fmaf(P[11], d2, fmaf(P[10], d1, fmaf(P[9],  d0, P[39]))); a0 = fmaf(P[52], fast_tanh(t), t);
  t = fmaf(P[14], d2, fmaf(P[13], d1, fmaf(P[12], d0, P[40]))); a1 = fmaf(P[53], fast_tanh(t), t);
  t = fmaf(P[17], d2, fmaf(P[16], d1, fmaf(P[15], d0, P[41]))); a2 = fmaf(P[54], fast_tanh(t), t);

  t = fmaf(P[20], a2, fmaf(P[19], a1, fmaf(P[18], a0, P[42]))); d0 = fmaf(P[55], fast_tanh(t), t);
  t = fmaf(P[23], a2, fmaf(P[22], a1, fmaf(P[21], a0, P[43]))); d1 = fmaf(P[56], fast_tanh(t), t);
  t = fmaf(P[26], a2, fmaf(P[25], a1, fmaf(P[24], a0, P[44]))); d2 = fmaf(P[57], fast_tanh(t), t);

  return fmaf(P[32], d2, fmaf(P[31], d1, fmaf(P[30], d0, P[45])));
}

// factors==0 path: every "logits + tanh(f)*tanh(logits)" collapses to identity.
__device__ __forceinline__ float mlp_fast(float v, const float* P) {
  float a0, a1, a2, d0, d1, d2;
  a0 = fmaf(P[27], v, P[33]);
  a1 = fmaf(P[28], v, P[34]);
  a2 = fmaf(P[29], v, P[35]);

  d0 = fmaf(P[2], a2, fmaf(P[1], a1, fmaf(P[0], a0, P[36])));
  d1 = fmaf(P[5], a2, fmaf(P[4], a1, fmaf(P[3], a0, P[37])));
  d2 = fmaf(P[8], a2, fmaf(P[7], a1, fmaf(P[6], a0, P[38])));

  a0 = fmaf(P[11], d2, fmaf(P[10], d1, fmaf(P[9],  d0, P[39])));
  a1 = fmaf(P[14], d2, fmaf(P[13], d1, fmaf(P[12], d0, P[40])));
  a2 = fmaf(P[17], d2, fmaf(P[16], d1, fmaf(P[15], d0, P[41])));

  d0 = fmaf(P[20], a2, fmaf(P[19], a1, fmaf(P[18], a0, P[42])));
  d1 = fmaf(P[23], a2, fmaf(P[22], a1, fmaf(P[21], a0, P[43])));
  d2 = fmaf(P[26], a2, fmaf(P[25], a1, fmaf(P[24], a0, P[44])));

  return fmaf(P[32], d2, fmaf(P[31], d1, fmaf(P[30], d0, P[45])));
}

__device__ __forceinline__ void load_tables(
    int t, int c,
    const float* __restrict__ sos_w, const float* __restrict__ sos_b,
    const float* __restrict__ m0, const float* __restrict__ m1,
    const float* __restrict__ m2, const float* __restrict__ m3,
    const float* __restrict__ m4,
    const float* __restrict__ c0, const float* __restrict__ c1,
    const float* __restrict__ c2, const float* __restrict__ c3,
    const float* __restrict__ c4,
    const float* __restrict__ f0, const float* __restrict__ f1,
    const float* __restrict__ f2, const float* __restrict__ f3,
    float* s_w, float* s_kb, float* s_pw, float* s_p)
{
  if (t < 68) {
    float w = (t < 60) ? sos_w[t] : 0.0f;
    float b = (t < 60) ? sos_b[t] : 0.0f;
    s_w[t]  = w;
    s_kb[t] = KSOS * b;
  }
  if (t >= 64 && t < 128) {
    int i = t - 64;
    float v = (i < 60) ? sos_w[i] : 0.0f;
    float s = v;
    #pragma unroll
    for (int off = 1; off < 64; off <<= 1) {
      float o = __shfl_up(s, off, 64);
      if (i >= off) s += o;
    }
    if (i <= 60) s_pw[i] = s - v;        // exclusive prefix: sum_{j<i} w_j
  }
  {
    int p = t - 128;
    if (p >= 0 && p < 58) {
      float val;
      if      (p <  9) val = softplus_f(m1[c*9 +  p      ]);
      else if (p < 18) val = softplus_f(m2[c*9 + (p -  9)]);
      else if (p < 27) val = softplus_f(m3[c*9 + (p - 18)]);
      else if (p < 30) val = softplus_f(m0[c*3 + (p - 27)]);
      else if (p < 33) val = softplus_f(m4[c*3 + (p - 30)]);
      else if (p < 36) val = c0[c*3 + (p - 33)];
      else if (p < 39) val = c1[c*3 + (p - 36)];
      else if (p < 42) val = c2[c*3 + (p - 39)];
      else if (p < 45) val = c3[c*3 + (p - 42)];
      else if (p < 46) val = c4[c];
      else if (p < 49) val = tanhf(f0[c*3 + (p - 46)]);
      else if (p < 52) val = tanhf(f1[c*3 + (p - 49)]);
      else if (p < 55) val = tanhf(f2[c*3 + (p - 52)]);
      else             val = tanhf(f3[c*3 + (p - 55)]);
      s_p[p] = val;
    }
  }
  __syncthreads();
}

// SoS staircase: windowed sum of sigmoids + exclusive prefix of saturated steps
__device__ __forceinline__ float sos_eval(
    float xx, const float* s_w, const float* s_kb, const float* s_pw)
{
  float kf = ceilf((xx + 9.32f) * INV_D);
  int k = (int)kf;
  k = max(0, min(60, k));
  float acc = s_pw[k];
  float kx  = KSOS * xx;
  #pragma unroll
  for (int i = 0; i < 6; ++i) {
    float z = s_kb[k + i] - kx;
    acc = fmaf(s_w[k + i], rcp_f(1.0f + exp2_f(z)), acc);
  }
  return acc - 10.0f;
}

template <bool FAST>
__device__ __forceinline__ float lik_from_y(float yq, const float* P) {
  float lo = FAST ? mlp_fast(yq - 0.5f, P) : mlp_full(yq - 0.5f, P);
  float up = FAST ? mlp_fast(yq + 0.5f, P) : mlp_full(yq + 0.5f, P);
  float lu = lo + up;
  float sg = (lu > 0.0f) ? -1.0f : ((lu < 0.0f) ? 1.0f : 0.0f);
  float lik = fabsf(fast_sigmoid(sg * up) - fast_sigmoid(sg * lo));
  return fmaxf(lik, 1e-9f);
}

// ---------------- Kernel 1: per-channel LUT build (192 blocks) ------------
__global__ __launch_bounds__(256)
void eb_build(const float* __restrict__ sos_w, const float* __restrict__ sos_b,
              const float* __restrict__ m0, const float* __restrict__ m1,
              const float* __restrict__ m2, const float* __restrict__ m3,
              const float* __restrict__ m4,
              const float* __restrict__ c0, const float* __restrict__ c1,
              const float* __restrict__ c2, const float* __restrict__ c3,
              const float* __restrict__ c4,
              const float* __restrict__ f0, const float* __restrict__ f1,
              const float* __restrict__ f2, const float* __restrict__ f3,
              float2* __restrict__ lut)
{
  __shared__ float s_w[68], s_kb[68], s_pw[64], s_p[58];
  const int t = threadIdx.x;
  const int c = blockIdx.x;

  load_tables(t, c, sos_w, sos_b, m0, m1, m2, m3, m4,
              c0, c1, c2, c3, c4, f0, f1, f2, f3, s_w, s_kb, s_pw, s_p);

  float P[58];
  #pragma unroll
  for (int i = 0; i < 58; ++i) P[i] = s_p[i];

  bool nofac = true;
  #pragma unroll
  for (int i = 46; i < 58; ++i) nofac &= (P[i] == 0.0f);

  float2* dst = lut + (size_t)c * LUT_L;
  if (nofac) {
    #pragma unroll
    for (int r = 0; r < LUT_L / 256; ++r) {
      int idx = t + 256 * r;
      float xg = LUT_X0 + (float)idx * LUT_H;
      float yq = sos_eval(xg, s_w, s_kb, s_pw);
      dst[idx] = make_float2(yq, lik_from_y<true>(yq, P));
    }
  } else {
    #pragma unroll
    for (int r = 0; r < LUT_L / 256; ++r) {
      int idx = t + 256 * r;
      float xg = LUT_X0 + (float)idx * LUT_H;
      float yq = sos_eval(xg, s_w, s_kb, s_pw);
      dst[idx] = make_float2(yq, lik_from_y<false>(yq, P));
    }
  }
}

// ---------------- Kernel 2: streaming gather + lerp (1536 blocks) ---------
__global__ __launch_bounds__(256)
void eb_gather(const float* __restrict__ x, const float2* __restrict__ lut,
               float* __restrict__ out)
{
  __shared__ float2 s_yl[LUT_L];      // 4 KB, AoS (y, lik)

  const int t     = threadIdx.x;
  const int plane = blockIdx.x;
  const int c     = plane % C_CH;
  const int base  = plane * HW_;

  // independent loads: x first, then LUT stage (one float4 each)
  float4 xv = reinterpret_cast<const float4*>(x + base)[t];
  float4 l4 = reinterpret_cast<const float4*>(lut + (size_t)c * LUT_L)[t];
  reinterpret_cast<float4*>(s_yl)[t] = l4;
  __syncthreads();

  float xs[4] = {xv.x, xv.y, xv.z, xv.w};
  float ys[4], ls[4];
  #pragma unroll
  for (int e = 0; e < 4; ++e) {
    float xx = fminf(fmaxf(xs[e], LUT_X0), LUT_X0 + LUT_SPAN);
    float u  = (xx - LUT_X0) * LUT_IH;
    int   i  = (int)u;
    i = min(i, LUT_L - 2);
    float fr = u - (float)i;
    float2 a = s_yl[i];
    float2 b = s_yl[i + 1];
    ys[e] = fmaf(fr, b.x - a.x, a.x);
    ls[e] = fmaf(fr, b.y - a.y, a.y);
  }

  reinterpret_cast<float4*>(out + base)[t]          = make_float4(ys[0], ys[1], ys[2], ys[3]);
  reinterpret_cast<float4*>(out + TOTAL_ + base)[t] = make_float4(ls[0], ls[1], ls[2], ls[3]);
}

// ---------------- Fallback: round-4 fused kernel --------------------------
__global__ __launch_bounds__(256)
void eb_fused(const float* __restrict__ x,
              const float* __restrict__ sos_w, const float* __restrict__ sos_b,
              const float* __restrict__ m0, const float* __restrict__ m1,
              const float* __restrict__ m2, const float* __restrict__ m3,
              const float* __restrict__ m4,
              const float* __restrict__ c0, const float* __restrict__ c1,
              const float* __restrict__ c2, const float* __restrict__ c3,
              const float* __restrict__ c4,
              const float* __restrict__ f0, const float* __restrict__ f1,
              const float* __restrict__ f2, const float* __restrict__ f3,
              float* __restrict__ out)
{
  __shared__ float s_w[68], s_kb[68], s_pw[64], s_p[58];
  __shared__ float s_y[LUT_L], s_l[LUT_L];

  const int t  = threadIdx.x;
  const int c  = blockIdx.x % C_CH;
  const int g  = blockIdx.x / C_CH;
  const int base0 = ((2 * g)     * C_CH + c) * HW_;
  const int base1 = ((2 * g + 1) * C_CH + c) * HW_;

  float4 xv0 = reinterpret_cast<const float4*>(x + base0)[t];
  float4 xv1 = reinterpret_cast<const float4*>(x + base1)[t];

  load_tables(t, c, sos_w, sos_b, m0, m1, m2, m3, m4,
              c0, c1, c2, c3, c4, f0, f1, f2, f3, s_w, s_kb, s_pw, s_p);

  float P[58];
  #pragma unroll
  for (int i = 0; i < 58; ++i) P[i] = s_p[i];

  bool nofac = true;
  #pragma unroll
  for (int i = 46; i < 58; ++i) nofac &= (P[i] == 0.0f);

  if (nofac) {
    #pragma unroll
    for (int r = 0; r < LUT_L / 256; ++r) {
      int idx = t + 256 * r;
      float xg = LUT_X0 + (float)idx * LUT_H;
      float yq = sos_eval(xg, s_w, s_kb, s_pw);
      s_y[idx] = yq;
      s_l[idx] = lik_from_y<true>(yq, P);
    }
  } else {
    #pragma unroll
    for (int r = 0; r < LUT_L / 256; ++r) {
      int idx = t + 256 * r;
      float xg = LUT_X0 + (float)idx * LUT_H;
      float yq = sos_eval(xg, s_w, s_kb, s_pw);
      s_y[idx] = yq;
      s_l[idx] = lik_from_y<false>(yq, P);
    }
  }
  __syncthreads();

  float4 xvs[PPB] = {xv0, xv1};
  int bases[PPB]  = {base0, base1};
  #pragma unroll
  for (int pl = 0; pl < PPB; ++pl) {
    float xs[4] = {xvs[pl].x, xvs[pl].y, xvs[pl].z, xvs[pl].w};
    float ys[4], ls[4];
    #pragma unroll
    for (int e = 0; e < 4; ++e) {
      float xx = fminf(fmaxf(xs[e], LUT_X0), LUT_X0 + LUT_SPAN);
      float u  = (xx - LUT_X0) * LUT_IH;
      int   i  = (int)u;
      i = min(i, LUT_L - 2);
      float fr = u - (float)i;
      float y0 = s_y[i], y1 = s_y[i + 1];
      float l0 = s_l[i], l1 = s_l[i + 1];
      ys[e] = fmaf(fr, y1 - y0, y0);
      ls[e] = fmaf(fr, l1 - l0, l0);
    }
    reinterpret_cast<float4*>(out + bases[pl])[t]          = make_float4(ys[0], ys[1], ys[2], ys[3]);
    reinterpret_cast<float4*>(out + TOTAL_ + bases[pl])[t] = make_float4(ls[0], ls[1], ls[2], ls[3]);
  }
}

extern "C" void kernel_launch(void* const* d_in, const int* in_sizes, int n_in,
                              void* d_out, int out_size, void* d_ws, size_t ws_size,
                              hipStream_t stream) {
  const float* x  = (const float*)d_in[0];
  const float* sw = (const float*)d_in[1];
  const float* sb = (const float*)d_in[2];
  const float *M[5], *B[5], *F[4];

  if (n_in >= 17 && in_sizes[4] == 1728) {
    // reference-signature order: m0..m4, c0..c4, f0..f3
    for (int i = 0; i < 5; ++i) M[i] = (const float*)d_in[3 + i];
    for (int i = 0; i < 5; ++i) B[i] = (const float*)d_in[8 + i];
    for (int i = 0; i < 4; ++i) F[i] = (const float*)d_in[13 + i];
  } else {
    // setup_inputs() dict order: m0,c0,f0, m1,c1,f1, ..., m4,c4
    M[0] = (const float*)d_in[3];  B[0] = (const float*)d_in[4];  F[0] = (const float*)d_in[5];
    M[1] = (const float*)d_in[6];  B[1] = (const float*)d_in[7];  F[1] = (const float*)d_in[8];
    M[2] = (const float*)d_in[9];  B[2] = (const float*)d_in[10]; F[2] = (const float*)d_in[11];
    M[3] = (const float*)d_in[12]; B[3] = (const float*)d_in[13]; F[3] = (const float*)d_in[14];
    M[4] = (const float*)d_in[15]; B[4] = (const float*)d_in[16];
  }

  const size_t lut_bytes = (size_t)C_CH * LUT_L * sizeof(float2);  // 768 KiB

  if (ws_size >= lut_bytes) {
    float2* lut = (float2*)d_ws;
    hipLaunchKernelGGL(eb_build, dim3(C_CH), dim3(256), 0, stream,
                       sw, sb, M[0], M[1], M[2], M[3], M[4],
                       B[0], B[1], B[2], B[3], B[4],
                       F[0], F[1], F[2], F[3], lut);
    hipLaunchKernelGGL(eb_gather, dim3(NPLANE), dim3(256), 0, stream,
                       x, lut, (float*)d_out);
  } else {
    hipLaunchKernelGGL(eb_fused, dim3(NBLK), dim3(256), 0, stream,
                       x, sw, sb, M[0], M[1], M[2], M[3], M[4],
                       B[0], B[1], B[2], B[3], B[4],
                       F[0], F[1], F[2], F[3], (float*)d_out);
  }
}

// Round 6
// 11.690 us; speedup vs baseline: 1.2811x; 1.2811x over previous
//
#include <hip/hip_runtime.h>
#include <math.h>

#define C_CH    192
#define HW_     1024
#define NPLANE  1536           // 8*192 planes of H*W=1024
#define TOTAL_  1572864        // 8*192*32*32
#define PPB     2              // planes per block (same channel)
#define NBLK    (NPLANE / PPB) // 768

#define LOG2E   1.4426950408889634f
#define KSOS    28.853900817779268f   /* 2*BETA*log2(e) = 20*log2(e) */
#define INV_D   2.95f                 /* 59/20: inverse spacing of sos_b grid */

#define LUT_L   512
#define LUT_X0  (-10.72f)
#define LUT_SPAN 21.44f
#define LUT_H   (LUT_SPAN / (LUT_L - 1))
#define LUT_IH  ((LUT_L - 1) / LUT_SPAN)

__device__ __forceinline__ float rcp_f(float v)  { return __builtin_amdgcn_rcpf(v); }
__device__ __forceinline__ float exp2_f(float v) { return __builtin_amdgcn_exp2f(v); }

__device__ __forceinline__ float fast_tanh(float z) {
  float e = exp2_f(z * (2.0f * LOG2E));
  return 1.0f - 2.0f * rcp_f(e + 1.0f);
}
__device__ __forceinline__ float fast_sigmoid(float z) {
  return rcp_f(1.0f + exp2_f(-z * LOG2E));
}
__device__ __forceinline__ float softplus_f(float v) {
  return log1pf(expf(v));
}

// s_p layout: [0..8]=sp1 [9..17]=sp2 [18..26]=sp3 [27..29]=sp0 [30..32]=sp4
//             [33..35]=b0 [36..38]=b1 [39..41]=b2 [42..44]=b3 [45]=b4
//             [46..48]=tf0 [49..51]=tf1 [52..54]=tf2 [55..57]=tf3
__device__ __forceinline__ float mlp_full(float v, const float* P) {
  float t, a0, a1, a2, d0, d1, d2;
  t = fmaf(P[27], v, P[33]); a0 = fmaf(P[46], fast_tanh(t), t);
  t = fmaf(P[28], v, P[34]); a1 = fmaf(P[47], fast_tanh(t), t);
  t = fmaf(P[29], v, P[35]); a2 = fmaf(P[48], fast_tanh(t), t);

  t = fmaf(P[2], a2, fmaf(P[1], a1, fmaf(P[0], a0, P[36]))); d0 = fmaf(P[49], fast_tanh(t), t);
  t = fmaf(P[5], a2, fmaf(P[4], a1, fmaf(P[3], a0, P[37]))); d1 = fmaf(P[50], fast_tanh(t), t);
  t = fmaf(P[8], a2, fmaf(P[7], a1, fmaf(P[6], a0, P[38]))); d2 = fmaf(P[51], fast_tanh(t), t);

  t = fmaf(P[11], d2, fmaf(P[10], d1, fmaf(P[9],  d0, P[39]))); a0 = fmaf(P[52], fast_tanh(t), t);
  t = fmaf(P[14], d2, fmaf(P[13], d1, fmaf(P[12], d0, P[40]))); a1 = fmaf(P[53], fast_tanh(t), t);
  t = fmaf(P[17], d2, fmaf(P[16], d1, fmaf(P[15], d0, P[41]))); a2 = fmaf(P[54], fast_tanh(t), t);

  t = fmaf(P[20], a2, fmaf(P[19], a1, fmaf(P[18], a0, P[42]))); d0 = fmaf(P[55], fast_tanh(t), t);
  t = fmaf(P[23], a2, fmaf(P[22], a1, fmaf(P[21], a0, P[43]))); d1 = fmaf(P[56], fast_tanh(t), t);
  t = fmaf(P[26], a2, fmaf(P[25], a1, fmaf(P[24], a0, P[44]))); d2 = fmaf(P[57], fast_tanh(t), t);

  return fmaf(P[32], d2, fmaf(P[31], d1, fmaf(P[30], d0, P[45])));
}

// factors==0 path: every "logits + tanh(f)*tanh(logits)" collapses to identity.
__device__ __forceinline__ float mlp_fast(float v, const float* P) {
  float a0, a1, a2, d0, d1, d2;
  a0 = fmaf(P[27], v, P[33]);
  a1 = fmaf(P[28], v, P[34]);
  a2 = fmaf(P[29], v, P[35]);

  d0 = fmaf(P[2], a2, fmaf(P[1], a1, fmaf(P[0], a0, P[36])));
  d1 = fmaf(P[5], a2, fmaf(P[4], a1, fmaf(P[3], a0, P[37])));
  d2 = fmaf(P[8], a2, fmaf(P[7], a1, fmaf(P[6], a0, P[38])));

  a0 = fmaf(P[11], d2, fmaf(P[10], d1, fmaf(P[9],  d0, P[39])));
  a1 = fmaf(P[14], d2, fmaf(P[13], d1, fmaf(P[12], d0, P[40])));
  a2 = fmaf(P[17], d2, fmaf(P[16], d1, fmaf(P[15], d0, P[41])));

  d0 = fmaf(P[20], a2, fmaf(P[19], a1, fmaf(P[18], a0, P[42])));
  d1 = fmaf(P[23], a2, fmaf(P[22], a1, fmaf(P[21], a0, P[43])));
  d2 = fmaf(P[26], a2, fmaf(P[25], a1, fmaf(P[24], a0, P[44])));

  return fmaf(P[32], d2, fmaf(P[31], d1, fmaf(P[30], d0, P[45])));
}

template <bool FAST>
__device__ __forceinline__ float lik_from_y(float yq, const float* P) {
  float lo = FAST ? mlp_fast(yq - 0.5f, P) : mlp_full(yq - 0.5f, P);
  float up = FAST ? mlp_fast(yq + 0.5f, P) : mlp_full(yq + 0.5f, P);
  float lu = lo + up;
  float sg = (lu > 0.0f) ? -1.0f : ((lu < 0.0f) ? 1.0f : 0.0f);
  float lik = fabsf(fast_sigmoid(sg * up) - fast_sigmoid(sg * lo));
  return fmaxf(lik, 1e-9f);
}

// SoS staircase, 5-step window centered on x (±2.5 steps; skipped-term
// error < 5e-8 per step).  Requires s_w/s_kb zero-padded to >= 65.
__device__ __forceinline__ float sos5(
    float xx, const float* s_w, const float* s_kb, const float* s_pw)
{
  float kf = ceilf((xx + 9.15254237f) * INV_D);   // ceil((x + 10 - 2.5*d)/d)
  int k = (int)kf;
  k = max(0, min(60, k));
  float acc = s_pw[k];
  float kx  = KSOS * xx;
  #pragma unroll
  for (int i = 0; i < 5; ++i) {
    float z = s_kb[k + i] - kx;
    acc = fmaf(s_w[k + i], rcp_f(1.0f + exp2_f(z)), acc);
  }
  return acc - 10.0f;
}

// ---------------- Fused kernel, phase-overlapped ---------------------------
// Phase plan: issue x + RAW param loads up front (in flight), build the
// channel-independent y-LUT from SoS tables, store y outputs (params still
// in flight), then transform params, build lik-LUT, store lik outputs.
__global__ __launch_bounds__(256)
void eb_fused2(const float* __restrict__ x,
               const float* __restrict__ sos_w, const float* __restrict__ sos_b,
               const float* __restrict__ m0, const float* __restrict__ m1,
               const float* __restrict__ m2, const float* __restrict__ m3,
               const float* __restrict__ m4,
               const float* __restrict__ c0, const float* __restrict__ c1,
               const float* __restrict__ c2, const float* __restrict__ c3,
               const float* __restrict__ c4,
               const float* __restrict__ f0, const float* __restrict__ f1,
               const float* __restrict__ f2, const float* __restrict__ f3,
               float* __restrict__ out)
{
  __shared__ float s_w[68], s_kb[68], s_pw[64], s_p[58];
  __shared__ float s_y[LUT_L], s_l[LUT_L];

  const int t  = threadIdx.x;
  const int c  = blockIdx.x % C_CH;
  const int g  = blockIdx.x / C_CH;
  const int base0 = ((2 * g)     * C_CH + c) * HW_;
  const int base1 = ((2 * g + 1) * C_CH + c) * HW_;

  // ---- issue independent global loads first: x planes + raw params ----
  float4 xv0 = reinterpret_cast<const float4*>(x + base0)[t];
  float4 xv1 = reinterpret_cast<const float4*>(x + base1)[t];

  const int p = t - 128;                 // lanes 128..185 own one param each
  const bool havep = (p >= 0 && p < 58);
  float raw = 0.0f;
  if (havep) {
    if      (p <  9) raw = m1[c*9 +  p      ];
    else if (p < 18) raw = m2[c*9 + (p -  9)];
    else if (p < 27) raw = m3[c*9 + (p - 18)];
    else if (p < 30) raw = m0[c*3 + (p - 27)];
    else if (p < 33) raw = m4[c*3 + (p - 30)];
    else if (p < 36) raw = c0[c*3 + (p - 33)];
    else if (p < 39) raw = c1[c*3 + (p - 36)];
    else if (p < 42) raw = c2[c*3 + (p - 39)];
    else if (p < 45) raw = c3[c*3 + (p - 42)];
    else if (p < 46) raw = c4[c];
    else if (p < 49) raw = f0[c*3 + (p - 46)];
    else if (p < 52) raw = f1[c*3 + (p - 49)];
    else if (p < 55) raw = f2[c*3 + (p - 52)];
    else             raw = f3[c*3 + (p - 55)];
  }

  // ---- SoS tables (coalesced) + prefix scan ----
  if (t < 68) {
    float w = (t < 60) ? sos_w[t] : 0.0f;
    float b = (t < 60) ? sos_b[t] : 0.0f;
    s_w[t]  = w;
    s_kb[t] = KSOS * b;
  }
  if (t >= 64 && t < 128) {
    int i = t - 64;
    float v = (i < 60) ? sos_w[i] : 0.0f;
    float s = v;
    #pragma unroll
    for (int off = 1; off < 64; off <<= 1) {
      float o = __shfl_up(s, off, 64);
      if (i >= off) s += o;
    }
    if (i <= 60) s_pw[i] = s - v;        // exclusive prefix: sum_{j<i} w_j
  }
  __syncthreads();

  // ---- build y-LUT (channel-independent; params not needed) ----
  #pragma unroll
  for (int r = 0; r < LUT_L / 256; ++r) {
    int idx = t + 256 * r;
    float xg = LUT_X0 + (float)idx * LUT_H;
    s_y[idx] = sos5(xg, s_w, s_kb, s_pw);
  }
  __syncthreads();

  // ---- lerp + store y for both planes; remember indices/fractions ----
  float xsv[8] = {xv0.x, xv0.y, xv0.z, xv0.w, xv1.x, xv1.y, xv1.z, xv1.w};
  int   ii[8];
  float ff[8];
  {
    float ys[8];
    #pragma unroll
    for (int e = 0; e < 8; ++e) {
      float xx = fminf(fmaxf(xsv[e], LUT_X0), LUT_X0 + LUT_SPAN);
      float u  = (xx - LUT_X0) * LUT_IH;
      int   i  = (int)u;
      i = min(i, LUT_L - 2);
      float fr = u - (float)i;
      ii[e] = i; ff[e] = fr;
      float y0 = s_y[i], y1 = s_y[i + 1];
      ys[e] = fmaf(fr, y1 - y0, y0);
    }
    reinterpret_cast<float4*>(out + base0)[t] = make_float4(ys[0], ys[1], ys[2], ys[3]);
    reinterpret_cast<float4*>(out + base1)[t] = make_float4(ys[4], ys[5], ys[6], ys[7]);
  }

  // ---- transform params (loads long since landed) ----
  if (havep) {
    float val;
    if      (p < 33) val = softplus_f(raw);
    else if (p < 46) val = raw;
    else             val = tanhf(raw);
    s_p[p] = val;
  }
  __syncthreads();

  float P[58];
  #pragma unroll
  for (int i = 0; i < 58; ++i) P[i] = s_p[i];

  bool nofac = true;
  #pragma unroll
  for (int i = 46; i < 58; ++i) nofac &= (P[i] == 0.0f);

  // ---- build lik-LUT from s_y ----
  if (nofac) {
    #pragma unroll
    for (int r = 0; r < LUT_L / 256; ++r) {
      int idx = t + 256 * r;
      s_l[idx] = lik_from_y<true>(s_y[idx], P);
    }
  } else {
    #pragma unroll
    for (int r = 0; r < LUT_L / 256; ++r) {
      int idx = t + 256 * r;
      s_l[idx] = lik_from_y<false>(s_y[idx], P);
    }
  }
  __syncthreads();

  // ---- lerp + store lik for both planes (reuse ii/ff) ----
  {
    float ls[8];
    #pragma unroll
    for (int e = 0; e < 8; ++e) {
      int   i  = ii[e];
      float fr = ff[e];
      float l0 = s_l[i], l1 = s_l[i + 1];
      ls[e] = fmaf(fr, l1 - l0, l0);
    }
    reinterpret_cast<float4*>(out + TOTAL_ + base0)[t] = make_float4(ls[0], ls[1], ls[2], ls[3]);
    reinterpret_cast<float4*>(out + TOTAL_ + base1)[t] = make_float4(ls[4], ls[5], ls[6], ls[7]);
  }
}

extern "C" void kernel_launch(void* const* d_in, const int* in_sizes, int n_in,
                              void* d_out, int out_size, void* d_ws, size_t ws_size,
                              hipStream_t stream) {
  const float* x  = (const float*)d_in[0];
  const float* sw = (const float*)d_in[1];
  const float* sb = (const float*)d_in[2];
  const float *M[5], *B[5], *F[4];

  if (n_in >= 17 && in_sizes[4] == 1728) {
    // reference-signature order: m0..m4, c0..c4, f0..f3
    for (int i = 0; i < 5; ++i) M[i] = (const float*)d_in[3 + i];
    for (int i = 0; i < 5; ++i) B[i] = (const float*)d_in[8 + i];
    for (int i = 0; i < 4; ++i) F[i] = (const float*)d_in[13 + i];
  } else {
    // setup_inputs() dict order: m0,c0,f0, m1,c1,f1, ..., m4,c4
    M[0] = (const float*)d_in[3];  B[0] = (const float*)d_in[4];  F[0] = (const float*)d_in[5];
    M[1] = (const float*)d_in[6];  B[1] = (const float*)d_in[7];  F[1] = (const float*)d_in[8];
    M[2] = (const float*)d_in[9];  B[2] = (const float*)d_in[10]; F[2] = (const float*)d_in[11];
    M[3] = (const float*)d_in[12]; B[3] = (const float*)d_in[13]; F[3] = (const float*)d_in[14];
    M[4] = (const float*)d_in[15]; B[4] = (const float*)d_in[16];
  }

  hipLaunchKernelGGL(eb_fused2, dim3(NBLK), dim3(256), 0, stream,
                     x, sw, sb,
                     M[0], M[1], M[2], M[3], M[4],
                     B[0], B[1], B[2], B[3], B[4],
                     F[0], F[1], F[2], F[3],
                     (float*)d_out);
}

// Round 7
// 11.662 us; speedup vs baseline: 1.2843x; 1.0025x over previous
//
#include <hip/hip_runtime.h>
#include <math.h>

#define C_CH    192
#define HW_     1024
#define NPLANE  1536           // 8*192 planes of H*W=1024
#define TOTAL_  1572864        // 8*192*32*32
#define PPB     2              // planes per block (same channel)
#define NBLK    (NPLANE / PPB) // 768

#define LOG2E   1.4426950408889634f
#define KSOS    28.853900817779268f   /* 2*BETA*log2(e) = 20*log2(e) */
#define INV_D   2.95f                 /* 59/20: inverse spacing of sos_b grid */

#define LUT_L   512
#define LUT_X0  (-10.72f)
#define LUT_SPAN 21.44f
#define LUT_H   (LUT_SPAN / (LUT_L - 1))
#define LUT_IH  ((LUT_L - 1) / LUT_SPAN)

__device__ __forceinline__ float rcp_f(float v)  { return __builtin_amdgcn_rcpf(v); }
__device__ __forceinline__ float exp2_f(float v) { return __builtin_amdgcn_exp2f(v); }

__device__ __forceinline__ float fast_tanh(float z) {
  float e = exp2_f(z * (2.0f * LOG2E));
  return 1.0f - 2.0f * rcp_f(e + 1.0f);
}
__device__ __forceinline__ float fast_sigmoid(float z) {
  return rcp_f(1.0f + exp2_f(-z * LOG2E));
}
__device__ __forceinline__ float softplus_f(float v) {
  return log1pf(expf(v));
}

// s_p layout: [0..8]=sp1 [9..17]=sp2 [18..26]=sp3 [27..29]=sp0 [30..32]=sp4
//             [33..35]=b0 [36..38]=b1 [39..41]=b2 [42..44]=b3 [45]=b4
//             [46..48]=tf0 [49..51]=tf1 [52..54]=tf2 [55..57]=tf3
__device__ __forceinline__ float mlp_full(float v, const float* P) {
  float t, a0, a1, a2, d0, d1, d2;
  t = fmaf(P[27], v, P[33]); a0 = fmaf(P[46], fast_tanh(t), t);
  t = fmaf(P[28], v, P[34]); a1 = fmaf(P[47], fast_tanh(t), t);
  t = fmaf(P[29], v, P[35]); a2 = fmaf(P[48], fast_tanh(t), t);

  t = fmaf(P[2], a2, fmaf(P[1], a1, fmaf(P[0], a0, P[36]))); d0 = fmaf(P[49], fast_tanh(t), t);
  t = fmaf(P[5], a2, fmaf(P[4], a1, fmaf(P[3], a0, P[37]))); d1 = fmaf(P[50], fast_tanh(t), t);
  t = fmaf(P[8], a2, fmaf(P[7], a1, fmaf(P[6], a0, P[38]))); d2 = fmaf(P[51], fast_tanh(t), t);

  t = fmaf(P[11], d2, fmaf(P[10], d1, fmaf(P[9],  d0, P[39]))); a0 = fmaf(P[52], fast_tanh(t), t);
  t = fmaf(P[14], d2, fmaf(P[13], d1, fmaf(P[12], d0, P[40]))); a1 = fmaf(P[53], fast_tanh(t), t);
  t = fmaf(P[17], d2, fmaf(P[16], d1, fmaf(P[15], d0, P[41]))); a2 = fmaf(P[54], fast_tanh(t), t);

  t = fmaf(P[20], a2, fmaf(P[19], a1, fmaf(P[18], a0, P[42]))); d0 = fmaf(P[55], fast_tanh(t), t);
  t = fmaf(P[23], a2, fmaf(P[22], a1, fmaf(P[21], a0, P[43]))); d1 = fmaf(P[56], fast_tanh(t), t);
  t = fmaf(P[26], a2, fmaf(P[25], a1, fmaf(P[24], a0, P[44]))); d2 = fmaf(P[57], fast_tanh(t), t);

  return fmaf(P[32], d2, fmaf(P[31], d1, fmaf(P[30], d0, P[45])));
}

// factors==0 path: every "logits + tanh(f)*tanh(logits)" collapses to identity.
__device__ __forceinline__ float mlp_fast(float v, const float* P) {
  float a0, a1, a2, d0, d1, d2;
  a0 = fmaf(P[27], v, P[33]);
  a1 = fmaf(P[28], v, P[34]);
  a2 = fmaf(P[29], v, P[35]);

  d0 = fmaf(P[2], a2, fmaf(P[1], a1, fmaf(P[0], a0, P[36])));
  d1 = fmaf(P[5], a2, fmaf(P[4], a1, fmaf(P[3], a0, P[37])));
  d2 = fmaf(P[8], a2, fmaf(P[7], a1, fmaf(P[6], a0, P[38])));

  a0 = fmaf(P[11], d2, fmaf(P[10], d1, fmaf(P[9],  d0, P[39])));
  a1 = fmaf(P[14], d2, fmaf(P[13], d1, fmaf(P[12], d0, P[40])));
  a2 = fmaf(P[17], d2, fmaf(P[16], d1, fmaf(P[15], d0, P[41])));

  d0 = fmaf(P[20], a2, fmaf(P[19], a1, fmaf(P[18], a0, P[42])));
  d1 = fmaf(P[23], a2, fmaf(P[22], a1, fmaf(P[21], a0, P[43])));
  d2 = fmaf(P[26], a2, fmaf(P[25], a1, fmaf(P[24], a0, P[44])));

  return fmaf(P[32], d2, fmaf(P[31], d1, fmaf(P[30], d0, P[45])));
}

template <bool FAST>
__device__ __forceinline__ float lik_from_y(float yq, const float* P) {
  float lo = FAST ? mlp_fast(yq - 0.5f, P) : mlp_full(yq - 0.5f, P);
  float up = FAST ? mlp_fast(yq + 0.5f, P) : mlp_full(yq + 0.5f, P);
  float lu = lo + up;
  float sg = (lu > 0.0f) ? -1.0f : ((lu < 0.0f) ? 1.0f : 0.0f);
  float lik = fabsf(fast_sigmoid(sg * up) - fast_sigmoid(sg * lo));
  return fmaxf(lik, 1e-9f);
}

// SoS staircase, 5-step window centered on x (±2.5 steps; skipped-term
// error < 5e-8 per step).  Requires s_w/s_kb zero-padded to >= 65.
__device__ __forceinline__ float sos5(
    float xx, const float* s_w, const float* s_kb, const float* s_pw)
{
  float kf = ceilf((xx + 9.15254237f) * INV_D);   // ceil((x + 10 - 2.5*d)/d)
  int k = (int)kf;
  k = max(0, min(60, k));
  float acc = s_pw[k];
  float kx  = KSOS * xx;
  #pragma unroll
  for (int i = 0; i < 5; ++i) {
    float z = s_kb[k + i] - kx;
    acc = fmaf(s_w[k + i], rcp_f(1.0f + exp2_f(z)), acc);
  }
  return acc - 10.0f;
}

// ---------------- Fused kernel, 2-barrier schedule -------------------------
// Phase 1: issue x loads; wave0 writes SoS tables, wave1 prefix-scans w,
//          wave2 loads+transforms+writes the 58 channel params.   SYNC.
// Phase 2: each thread builds its 2 owned LUT entries fully in registers
//          (y and lik never round-trip LDS separately) -> s_yl[idx].  SYNC.
// Phase 3: merged lerp (2x ds_read_b64 per element) + 4 float4 stores.
__global__ __launch_bounds__(256)
void eb_fused3(const float* __restrict__ x,
               const float* __restrict__ sos_w, const float* __restrict__ sos_b,
               const float* __restrict__ m0, const float* __restrict__ m1,
               const float* __restrict__ m2, const float* __restrict__ m3,
               const float* __restrict__ m4,
               const float* __restrict__ c0, const float* __restrict__ c1,
               const float* __restrict__ c2, const float* __restrict__ c3,
               const float* __restrict__ c4,
               const float* __restrict__ f0, const float* __restrict__ f1,
               const float* __restrict__ f2, const float* __restrict__ f3,
               float* __restrict__ out)
{
  __shared__ float  s_w[68], s_kb[68], s_pw[64], s_p[58];
  __shared__ float2 s_yl[LUT_L];        // 4 KB AoS (y, lik)

  const int t  = threadIdx.x;
  const int c  = blockIdx.x % C_CH;
  const int g  = blockIdx.x / C_CH;
  const int base0 = ((2 * g)     * C_CH + c) * HW_;
  const int base1 = ((2 * g + 1) * C_CH + c) * HW_;

  // ---- issue x loads first (consumed only in phase 3) ----
  float4 xv0 = reinterpret_cast<const float4*>(x + base0)[t];
  float4 xv1 = reinterpret_cast<const float4*>(x + base1)[t];

  // ---- wave 2: param load + transform + write ----
  const int p = t - 128;
  if (p >= 0 && p < 58) {
    float raw;
    if      (p <  9) raw = m1[c*9 +  p      ];
    else if (p < 18) raw = m2[c*9 + (p -  9)];
    else if (p < 27) raw = m3[c*9 + (p - 18)];
    else if (p < 30) raw = m0[c*3 + (p - 27)];
    else if (p < 33) raw = m4[c*3 + (p - 30)];
    else if (p < 36) raw = c0[c*3 + (p - 33)];
    else if (p < 39) raw = c1[c*3 + (p - 36)];
    else if (p < 42) raw = c2[c*3 + (p - 39)];
    else if (p < 45) raw = c3[c*3 + (p - 42)];
    else if (p < 46) raw = c4[c];
    else if (p < 49) raw = f0[c*3 + (p - 46)];
    else if (p < 52) raw = f1[c*3 + (p - 49)];
    else if (p < 55) raw = f2[c*3 + (p - 52)];
    else             raw = f3[c*3 + (p - 55)];
    float val;
    if      (p < 33) val = softplus_f(raw);
    else if (p < 46) val = raw;
    else             val = tanhf(raw);
    s_p[p] = val;
  }

  // ---- wave 0: SoS tables (coalesced) ----
  if (t < 68) {
    float w = (t < 60) ? sos_w[t] : 0.0f;
    float b = (t < 60) ? sos_b[t] : 0.0f;
    s_w[t]  = w;
    s_kb[t] = KSOS * b;
  }
  // ---- wave 1: exclusive prefix scan of w ----
  if (t >= 64 && t < 128) {
    int i = t - 64;
    float v = (i < 60) ? sos_w[i] : 0.0f;
    float s = v;
    #pragma unroll
    for (int off = 1; off < 64; off <<= 1) {
      float o = __shfl_up(s, off, 64);
      if (i >= off) s += o;
    }
    if (i <= 60) s_pw[i] = s - v;        // exclusive prefix: sum_{j<i} w_j
  }
  __syncthreads();

  // ---- phase 2: params to registers, build owned LUT entries ----
  float P[58];
  #pragma unroll
  for (int i = 0; i < 58; ++i) P[i] = s_p[i];

  bool nofac = true;
  #pragma unroll
  for (int i = 46; i < 58; ++i) nofac &= (P[i] == 0.0f);

  if (nofac) {
    #pragma unroll
    for (int r = 0; r < LUT_L / 256; ++r) {
      int idx = t + 256 * r;
      float xg = LUT_X0 + (float)idx * LUT_H;
      float yq = sos5(xg, s_w, s_kb, s_pw);
      s_yl[idx] = make_float2(yq, lik_from_y<true>(yq, P));
    }
  } else {
    #pragma unroll
    for (int r = 0; r < LUT_L / 256; ++r) {
      int idx = t + 256 * r;
      float xg = LUT_X0 + (float)idx * LUT_H;
      float yq = sos5(xg, s_w, s_kb, s_pw);
      s_yl[idx] = make_float2(yq, lik_from_y<false>(yq, P));
    }
  }
  __syncthreads();

  // ---- phase 3: merged lerp + stores ----
  float xsv[8] = {xv0.x, xv0.y, xv0.z, xv0.w, xv1.x, xv1.y, xv1.z, xv1.w};
  float ys[8], ls[8];
  #pragma unroll
  for (int e = 0; e < 8; ++e) {
    float xx = fminf(fmaxf(xsv[e], LUT_X0), LUT_X0 + LUT_SPAN);
    float u  = (xx - LUT_X0) * LUT_IH;
    int   i  = (int)u;
    i = min(i, LUT_L - 2);
    float fr = u - (float)i;
    float2 a = s_yl[i];
    float2 b = s_yl[i + 1];
    ys[e] = fmaf(fr, b.x - a.x, a.x);
    ls[e] = fmaf(fr, b.y - a.y, a.y);
  }

  reinterpret_cast<float4*>(out + base0)[t]          = make_float4(ys[0], ys[1], ys[2], ys[3]);
  reinterpret_cast<float4*>(out + base1)[t]          = make_float4(ys[4], ys[5], ys[6], ys[7]);
  reinterpret_cast<float4*>(out + TOTAL_ + base0)[t] = make_float4(ls[0], ls[1], ls[2], ls[3]);
  reinterpret_cast<float4*>(out + TOTAL_ + base1)[t] = make_float4(ls[4], ls[5], ls[6], ls[7]);
}

extern "C" void kernel_launch(void* const* d_in, const int* in_sizes, int n_in,
                              void* d_out, int out_size, void* d_ws, size_t ws_size,
                              hipStream_t stream) {
  const float* x  = (const float*)d_in[0];
  const float* sw = (const float*)d_in[1];
  const float* sb = (const float*)d_in[2];
  const float *M[5], *B[5], *F[4];

  if (n_in >= 17 && in_sizes[4] == 1728) {
    // reference-signature order: m0..m4, c0..c4, f0..f3
    for (int i = 0; i < 5; ++i) M[i] = (const float*)d_in[3 + i];
    for (int i = 0; i < 5; ++i) B[i] = (const float*)d_in[8 + i];
    for (int i = 0; i < 4; ++i) F[i] = (const float*)d_in[13 + i];
  } else {
    // setup_inputs() dict order: m0,c0,f0, m1,c1,f1, ..., m4,c4
    M[0] = (const float*)d_in[3];  B[0] = (const float*)d_in[4];  F[0] = (const float*)d_in[5];
    M[1] = (const float*)d_in[6];  B[1] = (const float*)d_in[7];  F[1] = (const float*)d_in[8];
    M[2] = (const float*)d_in[9];  B[2] = (const float*)d_in[10]; F[2] = (const float*)d_in[11];
    M[3] = (const float*)d_in[12]; B[3] = (const float*)d_in[13]; F[3] = (const float*)d_in[14];
    M[4] = (const float*)d_in[15]; B[4] = (const float*)d_in[16];
  }

  hipLaunchKernelGGL(eb_fused3, dim3(NBLK), dim3(256), 0, stream,
                     x, sw, sb,
                     M[0], M[1], M[2], M[3], M[4],
                     B[0], B[1], B[2], B[3], B[4],
                     F[0], F[1], F[2], F[3],
                     (float*)d_out);
}